// Round 4
// baseline (389.492 us; speedup 1.0000x reference)
//
#include <hip/hip_runtime.h>
#include <hip/hip_bf16.h>

#define NREF  4096
#define NTR   8192
#define NCOMB 12288
#define DIN   384
#define HID   1024
#define NE    4
#define ESTR  3456   // per-element compact row stride (E[count]=3072, +8 sigma pad)

typedef __attribute__((ext_vector_type(8))) short bf16x8;
typedef __attribute__((ext_vector_type(4))) short s16x4;
typedef __attribute__((ext_vector_type(4))) float f32x4;

// ---------------------------------------------------------------------------
// ws layout (bytes)
#define WS_CNT    0
#define WS_RCNT   16
#define WS_POST   256                                   // NTR*4 = 32768
#define WS_RIDX   (WS_POST + NTR*4)                     // NE*NREF*4 = 65536
#define WS_COMB   (WS_RIDX + NE*NREF*4)                 // NE*NCOMB*4 = 196608
#define WS_W1TH   524288
#define WS_W1TL   (WS_W1TH + NE*DIN*HID*2)              // +3145728
#define WS_XGH    (WS_W1TL + NE*DIN*HID*2)              // 6815744
#define WS_XGL    (WS_XGH + NE*ESTR*DIN*2)              // +10616832
#define WS_W2TH   WS_XGH                                 // alias: Xg dead after k_l1
#define WS_W2TL   WS_XGL
#define WS_H1H    (WS_XGL + NE*ESTR*DIN*2)              // 28049408
#define WS_H1L    (WS_H1H + (size_t)NE*ESTR*HID*2)      // +28311552
#define WS_HFIN   (WS_H1L + (size_t)NE*ESTR*HID*2)      // 84672512 (+55296)
// total ~84.8 MB
// ---------------------------------------------------------------------------

__device__ __forceinline__ short f2bf(float f) {
    unsigned u = __builtin_bit_cast(unsigned, f);
    unsigned r = (u + 0x7FFF + ((u >> 16) & 1)) >> 16;   // RNE
    return (short)r;
}
__device__ __forceinline__ float bf2f(short s) {
    unsigned u = ((unsigned)(unsigned short)s) << 16;
    return __builtin_bit_cast(float, u);
}
__device__ __forceinline__ void gload16(const void* g, void* l) {
    __builtin_amdgcn_global_load_lds(
        (const __attribute__((address_space(1))) void*)g,
        (__attribute__((address_space(3))) void*)l, 16, 0, 0);
}
__device__ __forceinline__ float celu1(float v) {
    return v > 0.f ? v : (expf(v) - 1.f);
}

// ---------------------------------------------------------------------------
__global__ void k_compact(const int* __restrict__ lr, const int* __restrict__ lt,
                          int* cnt, int* rcnt, int* comb, int* ridxP, int* post) {
    int i = blockIdx.x * 256 + threadIdx.x;
    if (i < NREF) {
        int e = lr[i] - 1;
        int q = atomicAdd(&cnt[e], 1);
        comb[e * NCOMB + q] = i;
        int p = atomicAdd(&rcnt[e], 1);
        ridxP[e * NREF + p] = i | (q << 16);     // ref id | compact pos
    } else if (i < NCOMB) {
        int t = i - NREF;
        int e = lt[t] - 1;
        int q = atomicAdd(&cnt[e], 1);
        comb[e * NCOMB + q] = NREF + t;
        post[t] = q;                              // train compact pos
    }
}

// Transpose + hi/lo split: W [e][K][N] f32 -> Th/Tl [e][N][K'] bf16.
// permK!=0 applies pi(k) = (k&~63)|((k&15)<<2)|((k>>4)&3) to the K index
// (must match k_l1's permuted H1 column store).
__global__ __launch_bounds__(256) void k_tr(const float* __restrict__ W,
                                            short* __restrict__ Th,
                                            short* __restrict__ Tl,
                                            int K, int N, int permK) {
    int e = blockIdx.z;
    __shared__ float s[32][33];
    int tx = threadIdx.x & 31, ty = threadIdx.x >> 5;
    int k0 = blockIdx.y * 32, n0 = blockIdx.x * 32;
    const float* src = W + (size_t)e * K * N;
#pragma unroll
    for (int i = 0; i < 32; i += 8)
        s[ty + i][tx] = src[(size_t)(k0 + ty + i) * N + n0 + tx];
    __syncthreads();
    int k = k0 + tx;
    int kk = permK ? ((k & ~63) | ((k & 15) << 2) | ((k >> 4) & 3)) : k;
#pragma unroll
    for (int i = 0; i < 32; i += 8) {
        float v = s[tx][ty + i];
        short hb = f2bf(v);
        short lb = f2bf(v - bf2f(hb));
        size_t o = ((size_t)e * N + n0 + ty + i) * K + kk;
        Th[o] = hb;
        Tl[o] = lb;
    }
}

// Gather x rows into compact per-element order + hi/lo split (zero-fill pad rows).
__global__ __launch_bounds__(256) void k_gather(
    const float* __restrict__ xr, const float* __restrict__ xt,
    const int* __restrict__ cnt, const int* __restrict__ comb,
    short* __restrict__ XgH, short* __restrict__ XgL) {
    int e = blockIdx.y;
    int m = blockIdx.x * 4 + (threadIdx.x >> 6);
    int lane = threadIdx.x & 63;
    size_t dst = ((size_t)e * ESTR + m) * DIN;
    if (m < cnt[e]) {
        int g = comb[e * NCOMB + m];
        const float* src = (g < NREF) ? (xr + (size_t)g * DIN)
                                      : (xt + (size_t)(g - NREF) * DIN);
#pragma unroll
        for (int c = lane * 2, it = 0; it < 3; c += 128, ++it) {
            float2 v = *(const float2*)(src + c);
            short2 h, l;
            h.x = f2bf(v.x); l.x = f2bf(v.x - bf2f(h.x));
            h.y = f2bf(v.y); l.y = f2bf(v.y - bf2f(h.y));
            *(short2*)(XgH + dst + c) = h;
            *(short2*)(XgL + dst + c) = l;
        }
    } else {
#pragma unroll
        for (int c = lane * 2, it = 0; it < 3; c += 128, ++it) {
            *(short2*)(XgH + dst + c) = short2{0, 0};
            *(short2*)(XgL + dst + c) = short2{0, 0};
        }
    }
}

// ---------------------------------------------------------------------------
// Layer 1: H1C[e][m] = celu(Xg[e][m] @ W1[e] + b1[e]); all-gload_lds staging.
// Tile 128x128, BK=32, 4 waves, 3x split-bf16 MFMA. H1 cols stored pi-permuted.
__global__ __launch_bounds__(256) void k_l1(
    const short* __restrict__ XgH, const short* __restrict__ XgL,
    const short* __restrict__ W1Th, const short* __restrict__ W1Tl,
    const float* __restrict__ b1, const int* __restrict__ cnt,
    short* __restrict__ H1h, short* __restrict__ H1l) {
    int e = blockIdx.z;
    int count = cnt[e];
    int m0 = blockIdx.x * 128;
    if (m0 >= count) return;
    int n0 = blockIdx.y * 128;

    __shared__ __align__(16) char smem[32768];
    int t = threadIdx.x, w = t >> 6, lane = t & 63;
    int wr = w >> 1, wc = w & 1;

    int srow = t >> 2, sx = t & 3, fB = (srow >> 1) & 3;
    size_t aoff0 = ((size_t)e * ESTR + m0 + srow) * DIN + (sx ^ fB) * 8;
    size_t aoff1 = aoff0 + (size_t)64 * DIN;
    size_t boff0 = ((size_t)e * HID + n0 + srow) * DIN + (sx ^ fB) * 8;
    size_t boff1 = boff0 + (size_t)64 * DIN;
    char* ldsW = smem + w * 1024;   // wave-uniform base; HW adds lane*16

    f32x4 acc[4][4] = {};

    for (int k0 = 0; k0 < DIN; k0 += 32) {
        gload16(XgH + aoff0 + k0, ldsW + 0);
        gload16(XgH + aoff1 + k0, ldsW + 4096);
        gload16(XgL + aoff0 + k0, ldsW + 8192);
        gload16(XgL + aoff1 + k0, ldsW + 12288);
        gload16(W1Th + boff0 + k0, ldsW + 16384);
        gload16(W1Th + boff1 + k0, ldsW + 20480);
        gload16(W1Tl + boff0 + k0, ldsW + 24576);
        gload16(W1Tl + boff1 + k0, ldsW + 28672);
        __syncthreads();

        bf16x8 ah[4], al[4], bh[4], bl[4];
#pragma unroll
        for (int m = 0; m < 4; m++) {
            int row = wr * 64 + m * 16 + (lane & 15);
            int off = row * 64 + ((((lane >> 4) ^ ((row >> 1) & 3))) << 4);
            ah[m] = *(const bf16x8*)(smem + off);
            al[m] = *(const bf16x8*)(smem + 8192 + off);
        }
#pragma unroll
        for (int n = 0; n < 4; n++) {
            int row = wc * 64 + n * 16 + (lane & 15);
            int off = row * 64 + ((((lane >> 4) ^ ((row >> 1) & 3))) << 4);
            bh[n] = *(const bf16x8*)(smem + 16384 + off);
            bl[n] = *(const bf16x8*)(smem + 24576 + off);
        }
#pragma unroll
        for (int m = 0; m < 4; m++)
#pragma unroll
            for (int n = 0; n < 4; n++) {
                acc[m][n] = __builtin_amdgcn_mfma_f32_16x16x32_bf16(ah[m], bh[n], acc[m][n], 0, 0, 0);
                acc[m][n] = __builtin_amdgcn_mfma_f32_16x16x32_bf16(al[m], bh[n], acc[m][n], 0, 0, 0);
                acc[m][n] = __builtin_amdgcn_mfma_f32_16x16x32_bf16(ah[m], bl[n], acc[m][n], 0, 0, 0);
            }
        __syncthreads();
    }

    // epilogue: bias+celu, split, permuted short4 store (pos = base64 + q*4 + n)
    int q = lane & 15;
    float bb[4];
#pragma unroll
    for (int n = 0; n < 4; n++) bb[n] = b1[e * HID + n0 + wc * 64 + n * 16 + q];
#pragma unroll
    for (int m = 0; m < 4; m++) {
        int rbase = m0 + wr * 64 + m * 16 + (lane >> 4) * 4;
#pragma unroll
        for (int r = 0; r < 4; r++) {
            int row = rbase + r;
            if (row < count) {
                s16x4 hv, lv;
#pragma unroll
                for (int n = 0; n < 4; n++) {
                    float v = celu1(acc[m][n][r] + bb[n]);
                    hv[n] = f2bf(v);
                    lv[n] = f2bf(v - bf2f(hv[n]));
                }
                size_t o = ((size_t)e * ESTR + row) * HID + n0 + wc * 64 + q * 4;
                *(s16x4*)(H1h + o) = hv;
                *(s16x4*)(H1l + o) = lv;
            }
        }
    }
}

// ---------------------------------------------------------------------------
// Layers 2+3 fused: hfinC[e][m] += sum_col celu(H1C[e][m]@W2[:,col]+b2[col])*W3[col]
__global__ __launch_bounds__(256) void k_l23(
    const short* __restrict__ H1h, const short* __restrict__ H1l,
    const short* __restrict__ W2Th, const short* __restrict__ W2Tl,
    const float* __restrict__ b2, const float* __restrict__ W3,
    const int* __restrict__ cnt, float* __restrict__ hfinC) {
    int e = blockIdx.z;
    int count = cnt[e];
    int m0 = blockIdx.x * 128;
    if (m0 >= count) return;
    int n0 = blockIdx.y * 128;

    __shared__ __align__(16) char smem[32768];
    int t = threadIdx.x, w = t >> 6, lane = t & 63;
    int wr = w >> 1, wc = w & 1;

    int srow = t >> 2, sx = t & 3, f0 = (srow >> 1) & 3;
    size_t aoff0 = ((size_t)e * ESTR + m0 + srow) * HID + (sx ^ f0) * 8;
    size_t aoff1 = aoff0 + (size_t)64 * HID;
    size_t boff0 = ((size_t)e * HID + n0 + srow) * HID + (sx ^ f0) * 8;
    size_t boff1 = boff0 + (size_t)64 * HID;
    char* ldsW = smem + w * 1024;

    f32x4 acc[4][4] = {};

    for (int k0 = 0; k0 < HID; k0 += 32) {
        gload16(H1h + aoff0 + k0, ldsW + 0);
        gload16(H1h + aoff1 + k0, ldsW + 4096);
        gload16(H1l + aoff0 + k0, ldsW + 8192);
        gload16(H1l + aoff1 + k0, ldsW + 12288);
        gload16(W2Th + boff0 + k0, ldsW + 16384);
        gload16(W2Th + boff1 + k0, ldsW + 20480);
        gload16(W2Tl + boff0 + k0, ldsW + 24576);
        gload16(W2Tl + boff1 + k0, ldsW + 28672);
        __syncthreads();

        bf16x8 ah[4], al[4], bh[4], bl[4];
#pragma unroll
        for (int m = 0; m < 4; m++) {
            int row = wr * 64 + m * 16 + (lane & 15);
            int off = row * 64 + ((((lane >> 4) ^ ((row >> 1) & 3))) << 4);
            ah[m] = *(const bf16x8*)(smem + off);
            al[m] = *(const bf16x8*)(smem + 8192 + off);
        }
#pragma unroll
        for (int n = 0; n < 4; n++) {
            int row = wc * 64 + n * 16 + (lane & 15);
            int off = row * 64 + ((((lane >> 4) ^ ((row >> 1) & 3))) << 4);
            bh[n] = *(const bf16x8*)(smem + 16384 + off);
            bl[n] = *(const bf16x8*)(smem + 24576 + off);
        }
#pragma unroll
        for (int m = 0; m < 4; m++)
#pragma unroll
            for (int n = 0; n < 4; n++) {
                acc[m][n] = __builtin_amdgcn_mfma_f32_16x16x32_bf16(ah[m], bh[n], acc[m][n], 0, 0, 0);
                acc[m][n] = __builtin_amdgcn_mfma_f32_16x16x32_bf16(al[m], bh[n], acc[m][n], 0, 0, 0);
                acc[m][n] = __builtin_amdgcn_mfma_f32_16x16x32_bf16(ah[m], bl[n], acc[m][n], 0, 0, 0);
            }
        __syncthreads();
    }

    // epilogue: celu + W3-weight, reduce over 128 cols of this tile
    float s[4][4] = {};
#pragma unroll
    for (int n = 0; n < 4; n++) {
        int col = n0 + wc * 64 + n * 16 + (lane & 15);
        float bbv = b2[e * HID + col];
        float w3 = W3[e * HID + col];
#pragma unroll
        for (int m = 0; m < 4; m++)
#pragma unroll
            for (int r = 0; r < 4; r++)
                s[m][r] += celu1(acc[m][n][r] + bbv) * w3;
    }
#pragma unroll
    for (int m = 0; m < 4; m++)
#pragma unroll
        for (int r = 0; r < 4; r++) {
#pragma unroll
            for (int off = 8; off > 0; off >>= 1)
                s[m][r] += __shfl_xor(s[m][r], off, 64);
        }
    if ((lane & 15) == 0) {
#pragma unroll
        for (int m = 0; m < 4; m++) {
            int rbase = m0 + wr * 64 + m * 16 + (lane >> 4) * 4;
#pragma unroll
            for (int r = 0; r < 4; r++)
                if (rbase + r < count)
                    atomicAdd(&hfinC[e * ESTR + rbase + r], s[m][r]);
        }
    }
}

// ---------------------------------------------------------------------------
__global__ __launch_bounds__(256) void k_out(
    const int* __restrict__ lt, const float* __restrict__ yref,
    const float* __restrict__ alpha, const int* __restrict__ rcnt,
    const int* __restrict__ ridxP, const int* __restrict__ post,
    const float* __restrict__ hfinC, float* __restrict__ out) {
    int t = blockIdx.x * 4 + (threadIdx.x >> 6);
    int lane = threadIdx.x & 63;
    if (t >= NTR) return;
    int lab = lt[t];
    int e = lab - 1;
    float ht = hfinC[e * ESTR + post[t]];
    float a = alpha[e];
    int n = rcnt[e];
    const int* lst = ridxP + e * NREF;
    float num = 0.f, den = 0.f;
    for (int i = lane; i < n; i += 64) {
        int pk = lst[i];
        int r = pk & 0xFFFF;
        int pq = pk >> 16;
        float d = fabsf(ht - hfinC[e * ESTR + pq]);
        float p = expf(-a * d);
        num += p * yref[r];
        den += p;
    }
#pragma unroll
    for (int o = 32; o > 0; o >>= 1) {
        num += __shfl_down(num, o, 64);
        den += __shfl_down(den, o, 64);
    }
    if (lane == 0) {
        out[t] = (float)lab;
        out[NTR + t] = num / den;
    }
}

extern "C" void kernel_launch(void* const* d_in, const int* in_sizes, int n_in,
                              void* d_out, int out_size, void* d_ws, size_t ws_size,
                              hipStream_t stream) {
    const float* xr    = (const float*)d_in[0];
    const float* yref  = (const float*)d_in[1];
    const int*   lr    = (const int*)  d_in[2];
    const float* xt    = (const float*)d_in[3];
    const int*   lt    = (const int*)  d_in[4];
    const float* W1    = (const float*)d_in[5];
    const float* b1    = (const float*)d_in[6];
    const float* W2    = (const float*)d_in[7];
    const float* b2    = (const float*)d_in[8];
    const float* W3    = (const float*)d_in[9];
    // d_in[10] = b3 (cancels in |ht-hr|), d_in[11] = alpha
    const float* alpha = (const float*)d_in[11];

    char* ws = (char*)d_ws;
    int*   cnt   = (int*)(ws + WS_CNT);
    int*   rcnt  = (int*)(ws + WS_RCNT);
    int*   post  = (int*)(ws + WS_POST);
    int*   ridxP = (int*)(ws + WS_RIDX);
    int*   comb  = (int*)(ws + WS_COMB);
    short* W1Th  = (short*)(ws + WS_W1TH);
    short* W1Tl  = (short*)(ws + WS_W1TL);
    short* XgH   = (short*)(ws + WS_XGH);
    short* XgL   = (short*)(ws + WS_XGL);
    short* W2Th  = (short*)(ws + WS_W2TH);   // aliases XgH (Xg dead after k_l1)
    short* W2Tl  = (short*)(ws + WS_W2TL);   // aliases XgL
    short* H1h   = (short*)(ws + WS_H1H);
    short* H1l   = (short*)(ws + WS_H1L);
    float* hfinC = (float*)(ws + WS_HFIN);
    float* out   = (float*)d_out;

    hipMemsetAsync(ws, 0, 32, stream);                      // cnt + rcnt
    hipMemsetAsync(hfinC, 0, NE * ESTR * 4, stream);

    k_compact<<<NCOMB / 256, 256, 0, stream>>>(lr, lt, cnt, rcnt, comb, ridxP, post);

    k_tr<<<dim3(HID / 32, DIN / 32, NE), 256, 0, stream>>>(W1, W1Th, W1Tl, DIN, HID, 0);
    k_gather<<<dim3(ESTR / 4, NE), 256, 0, stream>>>(xr, xt, cnt, comb, XgH, XgL);

    k_l1<<<dim3(ESTR / 128, HID / 128, NE), 256, 0, stream>>>(
        XgH, XgL, W1Th, W1Tl, b1, cnt, H1h, H1l);

    // W2 transpose AFTER k_l1 (it overwrites the Xg region)
    k_tr<<<dim3(HID / 32, HID / 32, NE), 256, 0, stream>>>(W2, W2Th, W2Tl, HID, HID, 1);

    k_l23<<<dim3(ESTR / 128, HID / 128, NE), 256, 0, stream>>>(
        H1h, H1l, W2Th, W2Tl, b2, W3, cnt, hfinC);

    k_out<<<NTR / 4, 256, 0, stream>>>(lt, yref, alpha, rcnt, ridxP, post, hfinC, out);
}

// Round 5
// 376.190 us; speedup vs baseline: 1.0354x; 1.0354x over previous
//
#include <hip/hip_runtime.h>
#include <hip/hip_bf16.h>

#define NREF  4096
#define NTR   8192
#define NCOMB 12288
#define DIN   384
#define HID   1024
#define NE    4
#define ESTR  3456   // per-element compact row stride (count~3072, +pad)
#define MT    (ESTR / 128)   // 27 m-tiles

typedef __attribute__((ext_vector_type(8))) short bf16x8;
typedef __attribute__((ext_vector_type(4))) short s16x4;
typedef __attribute__((ext_vector_type(4))) float f32x4;

// ---------------------------------------------------------------------------
// ws layout (bytes)
#define WS_CNT    0
#define WS_RCNT   16
#define WS_POST   256                                   // NTR*4 = 32768
#define WS_RIDX   (WS_POST + NTR*4)                     // NE*NREF*4 = 65536
#define WS_COMB   (WS_RIDX + NE*NREF*4)                 // NE*NCOMB*4 = 196608
#define WS_W1TH   524288
#define WS_W1TL   (WS_W1TH + NE*DIN*HID*2)              // +3145728
#define WS_XGH    (WS_W1TL + NE*DIN*HID*2)              // 6815744
#define WS_XGL    (WS_XGH + NE*ESTR*DIN*2)              // +10616832
#define WS_W2TH   WS_XGH                                 // alias: Xg dead after k_l1
#define WS_W2TL   WS_XGL
#define WS_H1H    (WS_XGL + NE*ESTR*DIN*2)              // 28049408
#define WS_H1L    (WS_H1H + (size_t)NE*ESTR*HID*2)      // +28311552
#define WS_HFIN   (WS_H1L + (size_t)NE*ESTR*HID*2)      // 84672512 (+55296)
// total ~84.8 MB
// ---------------------------------------------------------------------------

__device__ __forceinline__ short f2bf(float f) {
    unsigned u = __builtin_bit_cast(unsigned, f);
    unsigned r = (u + 0x7FFF + ((u >> 16) & 1)) >> 16;   // RNE
    return (short)r;
}
__device__ __forceinline__ float bf2f(short s) {
    unsigned u = ((unsigned)(unsigned short)s) << 16;
    return __builtin_bit_cast(float, u);
}
__device__ __forceinline__ void gload16(const void* g, void* l) {
    __builtin_amdgcn_global_load_lds(
        (const __attribute__((address_space(1))) void*)g,
        (__attribute__((address_space(3))) void*)l, 16, 0, 0);
}
__device__ __forceinline__ float celu1(float v) {
    return v > 0.f ? v : (expf(v) - 1.f);
}

// ---------------------------------------------------------------------------
__global__ void k_compact(const int* __restrict__ lr, const int* __restrict__ lt,
                          int* cnt, int* rcnt, int* comb, int* ridxP, int* post) {
    int i = blockIdx.x * 256 + threadIdx.x;
    if (i < NREF) {
        int e = lr[i] - 1;
        int q = atomicAdd(&cnt[e], 1);
        comb[e * NCOMB + q] = i;
        int p = atomicAdd(&rcnt[e], 1);
        ridxP[e * NREF + p] = i | (q << 16);     // ref id | compact pos
    } else if (i < NCOMB) {
        int t = i - NREF;
        int e = lt[t] - 1;
        int q = atomicAdd(&cnt[e], 1);
        comb[e * NCOMB + q] = NREF + t;
        post[t] = q;                              // train compact pos
    }
}

// ---------------------------------------------------------------------------
// Fused prep: [0,1536) W1 transpose+split; [1536,4992) x gather+split;
// [4992,4996) zero hfin. One launch instead of three (graph-node/flush cost).
#define PREP_TR1  1536                     // (HID/32)*(DIN/32)*NE
#define PREP_GAT  (PREP_TR1 + ESTR/4*NE)   // +3456
#define PREP_ZERO (PREP_GAT + 4)
__global__ __launch_bounds__(256) void k_prep(
    const float* __restrict__ W1,
    const float* __restrict__ xr, const float* __restrict__ xt,
    const int* __restrict__ cnt, const int* __restrict__ comb,
    short* __restrict__ W1Th, short* __restrict__ W1Tl,
    short* __restrict__ XgH, short* __restrict__ XgL,
    float* __restrict__ hfinC) {
    __shared__ float s[32][33];
    int b = blockIdx.x;
    if (b < PREP_TR1) {
        // W1 [e][K=384][N=1024] -> W1T hi/lo [e][N][K]
        int e = b / 384, r = b % 384;
        int n0 = (r & 31) * 32, k0 = (r >> 5) * 32;
        int tx = threadIdx.x & 31, ty = threadIdx.x >> 5;
        const float* src = W1 + (size_t)e * DIN * HID;
#pragma unroll
        for (int i = 0; i < 32; i += 8)
            s[ty + i][tx] = src[(size_t)(k0 + ty + i) * HID + n0 + tx];
        __syncthreads();
#pragma unroll
        for (int i = 0; i < 32; i += 8) {
            float v = s[tx][ty + i];
            short hb = f2bf(v);
            short lb = f2bf(v - bf2f(hb));
            size_t o = ((size_t)e * HID + n0 + ty + i) * DIN + k0 + tx;
            W1Th[o] = hb;
            W1Tl[o] = lb;
        }
    } else if (b < PREP_GAT) {
        int b2 = b - PREP_TR1;
        int e = b2 / (ESTR / 4);
        int m = (b2 % (ESTR / 4)) * 4 + (threadIdx.x >> 6);
        int lane = threadIdx.x & 63;
        size_t dst = ((size_t)e * ESTR + m) * DIN;
        if (m < cnt[e]) {
            int g = comb[e * NCOMB + m];
            const float* src = (g < NREF) ? (xr + (size_t)g * DIN)
                                          : (xt + (size_t)(g - NREF) * DIN);
#pragma unroll
            for (int c = lane * 2, it = 0; it < 3; c += 128, ++it) {
                float2 v = *(const float2*)(src + c);
                short2 h, l;
                h.x = f2bf(v.x); l.x = f2bf(v.x - bf2f(h.x));
                h.y = f2bf(v.y); l.y = f2bf(v.y - bf2f(h.y));
                *(short2*)(XgH + dst + c) = h;
                *(short2*)(XgL + dst + c) = l;
            }
        } else {
#pragma unroll
            for (int c = lane * 2, it = 0; it < 3; c += 128, ++it) {
                *(short2*)(XgH + dst + c) = short2{0, 0};
                *(short2*)(XgL + dst + c) = short2{0, 0};
            }
        }
    } else {
        int idx = (b - PREP_GAT) * 1024 + threadIdx.x;   // one float4 per thread
        if (idx * 4 < NE * ESTR) {
            f32x4 z = {0.f, 0.f, 0.f, 0.f};
            *(f32x4*)(hfinC + idx * 4) = z;
        }
    }
}

// W2 transpose + hi/lo split with permuted K (must run between l1 and l23:
// output aliases the Xg region). pi(k) = (k&~63)|((k&15)<<2)|((k>>4)&3).
__global__ __launch_bounds__(256) void k_tr2(const float* __restrict__ W,
                                             short* __restrict__ Th,
                                             short* __restrict__ Tl) {
    int e = blockIdx.z;
    __shared__ float s[32][33];
    int tx = threadIdx.x & 31, ty = threadIdx.x >> 5;
    int k0 = blockIdx.y * 32, n0 = blockIdx.x * 32;
    const float* src = W + (size_t)e * HID * HID;
#pragma unroll
    for (int i = 0; i < 32; i += 8)
        s[ty + i][tx] = src[(size_t)(k0 + ty + i) * HID + n0 + tx];
    __syncthreads();
    int k = k0 + tx;
    int kk = (k & ~63) | ((k & 15) << 2) | ((k >> 4) & 3);
#pragma unroll
    for (int i = 0; i < 32; i += 8) {
        float v = s[tx][ty + i];
        short hb = f2bf(v);
        short lb = f2bf(v - bf2f(hb));
        size_t o = ((size_t)e * HID + n0 + ty + i) * HID + kk;
        Th[o] = hb;
        Tl[o] = lb;
    }
}

// ---------------------------------------------------------------------------
// Layer 1: H1C[e][m] = celu(Xg[e][m] @ W1[e] + b1[e]).
// 1-D grid, XCD-pinned n-panels: n-tile = bid&7 (8 n-tiles = 8 XCDs, bid%8
// round-robins XCDs) so each B-panel is read by exactly one XCD's L2.
__global__ __launch_bounds__(256) void k_l1(
    const short* __restrict__ XgH, const short* __restrict__ XgL,
    const short* __restrict__ W1Th, const short* __restrict__ W1Tl,
    const float* __restrict__ b1, const int* __restrict__ cnt,
    short* __restrict__ H1h, short* __restrict__ H1l) {
    int bid = blockIdx.x;
    int n0 = (bid & 7) * 128;
    int rest = bid >> 3;
    int e = rest / MT;
    int count = cnt[e];
    int m0 = (rest % MT) * 128;
    if (m0 >= count) return;

    __shared__ __align__(16) char smem[32768];
    int t = threadIdx.x, w = t >> 6, lane = t & 63;
    int wr = w >> 1, wc = w & 1;

    int srow = t >> 2, sx = t & 3, fB = (srow >> 1) & 3;
    size_t aoff0 = ((size_t)e * ESTR + m0 + srow) * DIN + (sx ^ fB) * 8;
    size_t aoff1 = aoff0 + (size_t)64 * DIN;
    size_t boff0 = ((size_t)e * HID + n0 + srow) * DIN + (sx ^ fB) * 8;
    size_t boff1 = boff0 + (size_t)64 * DIN;
    char* ldsW = smem + w * 1024;   // wave-uniform base; HW adds lane*16

    f32x4 acc[4][4] = {};

    for (int k0 = 0; k0 < DIN; k0 += 32) {
        gload16(XgH + aoff0 + k0, ldsW + 0);
        gload16(XgH + aoff1 + k0, ldsW + 4096);
        gload16(XgL + aoff0 + k0, ldsW + 8192);
        gload16(XgL + aoff1 + k0, ldsW + 12288);
        gload16(W1Th + boff0 + k0, ldsW + 16384);
        gload16(W1Th + boff1 + k0, ldsW + 20480);
        gload16(W1Tl + boff0 + k0, ldsW + 24576);
        gload16(W1Tl + boff1 + k0, ldsW + 28672);
        __syncthreads();

        bf16x8 ah[4], al[4], bh[4], bl[4];
#pragma unroll
        for (int m = 0; m < 4; m++) {
            int row = wr * 64 + m * 16 + (lane & 15);
            int off = row * 64 + ((((lane >> 4) ^ ((row >> 1) & 3))) << 4);
            ah[m] = *(const bf16x8*)(smem + off);
            al[m] = *(const bf16x8*)(smem + 8192 + off);
        }
#pragma unroll
        for (int n = 0; n < 4; n++) {
            int row = wc * 64 + n * 16 + (lane & 15);
            int off = row * 64 + ((((lane >> 4) ^ ((row >> 1) & 3))) << 4);
            bh[n] = *(const bf16x8*)(smem + 16384 + off);
            bl[n] = *(const bf16x8*)(smem + 24576 + off);
        }
#pragma unroll
        for (int m = 0; m < 4; m++)
#pragma unroll
            for (int n = 0; n < 4; n++) {
                acc[m][n] = __builtin_amdgcn_mfma_f32_16x16x32_bf16(ah[m], bh[n], acc[m][n], 0, 0, 0);
                acc[m][n] = __builtin_amdgcn_mfma_f32_16x16x32_bf16(al[m], bh[n], acc[m][n], 0, 0, 0);
                acc[m][n] = __builtin_amdgcn_mfma_f32_16x16x32_bf16(ah[m], bl[n], acc[m][n], 0, 0, 0);
            }
        __syncthreads();
    }

    // epilogue: bias+celu, split, permuted short4 store (pos = base64 + q*4 + n)
    int q = lane & 15;
    float bb[4];
#pragma unroll
    for (int n = 0; n < 4; n++) bb[n] = b1[e * HID + n0 + wc * 64 + n * 16 + q];
#pragma unroll
    for (int m = 0; m < 4; m++) {
        int rbase = m0 + wr * 64 + m * 16 + (lane >> 4) * 4;
#pragma unroll
        for (int r = 0; r < 4; r++) {
            int row = rbase + r;
            if (row < count) {
                s16x4 hv, lv;
#pragma unroll
                for (int n = 0; n < 4; n++) {
                    float v = celu1(acc[m][n][r] + bb[n]);
                    hv[n] = f2bf(v);
                    lv[n] = f2bf(v - bf2f(hv[n]));
                }
                size_t o = ((size_t)e * ESTR + row) * HID + n0 + wc * 64 + q * 4;
                *(s16x4*)(H1h + o) = hv;
                *(s16x4*)(H1l + o) = lv;
            }
        }
    }
}

// ---------------------------------------------------------------------------
// Layers 2+3 fused: hfinC[e][m] += sum_col celu(H1C[e][m]@W2[:,col]+b2[col])*W3[col]
// Same XCD n-panel pinning as k_l1.
__global__ __launch_bounds__(256) void k_l23(
    const short* __restrict__ H1h, const short* __restrict__ H1l,
    const short* __restrict__ W2Th, const short* __restrict__ W2Tl,
    const float* __restrict__ b2, const float* __restrict__ W3,
    const int* __restrict__ cnt, float* __restrict__ hfinC) {
    int bid = blockIdx.x;
    int n0 = (bid & 7) * 128;
    int rest = bid >> 3;
    int e = rest / MT;
    int count = cnt[e];
    int m0 = (rest % MT) * 128;
    if (m0 >= count) return;

    __shared__ __align__(16) char smem[32768];
    int t = threadIdx.x, w = t >> 6, lane = t & 63;
    int wr = w >> 1, wc = w & 1;

    int srow = t >> 2, sx = t & 3, f0 = (srow >> 1) & 3;
    size_t aoff0 = ((size_t)e * ESTR + m0 + srow) * HID + (sx ^ f0) * 8;
    size_t aoff1 = aoff0 + (size_t)64 * HID;
    size_t boff0 = ((size_t)e * HID + n0 + srow) * HID + (sx ^ f0) * 8;
    size_t boff1 = boff0 + (size_t)64 * HID;
    char* ldsW = smem + w * 1024;

    f32x4 acc[4][4] = {};

    for (int k0 = 0; k0 < HID; k0 += 32) {
        gload16(H1h + aoff0 + k0, ldsW + 0);
        gload16(H1h + aoff1 + k0, ldsW + 4096);
        gload16(H1l + aoff0 + k0, ldsW + 8192);
        gload16(H1l + aoff1 + k0, ldsW + 12288);
        gload16(W2Th + boff0 + k0, ldsW + 16384);
        gload16(W2Th + boff1 + k0, ldsW + 20480);
        gload16(W2Tl + boff0 + k0, ldsW + 24576);
        gload16(W2Tl + boff1 + k0, ldsW + 28672);
        __syncthreads();

        bf16x8 ah[4], al[4], bh[4], bl[4];
#pragma unroll
        for (int m = 0; m < 4; m++) {
            int row = wr * 64 + m * 16 + (lane & 15);
            int off = row * 64 + ((((lane >> 4) ^ ((row >> 1) & 3))) << 4);
            ah[m] = *(const bf16x8*)(smem + off);
            al[m] = *(const bf16x8*)(smem + 8192 + off);
        }
#pragma unroll
        for (int n = 0; n < 4; n++) {
            int row = wc * 64 + n * 16 + (lane & 15);
            int off = row * 64 + ((((lane >> 4) ^ ((row >> 1) & 3))) << 4);
            bh[n] = *(const bf16x8*)(smem + 16384 + off);
            bl[n] = *(const bf16x8*)(smem + 24576 + off);
        }
#pragma unroll
        for (int m = 0; m < 4; m++)
#pragma unroll
            for (int n = 0; n < 4; n++) {
                acc[m][n] = __builtin_amdgcn_mfma_f32_16x16x32_bf16(ah[m], bh[n], acc[m][n], 0, 0, 0);
                acc[m][n] = __builtin_amdgcn_mfma_f32_16x16x32_bf16(al[m], bh[n], acc[m][n], 0, 0, 0);
                acc[m][n] = __builtin_amdgcn_mfma_f32_16x16x32_bf16(ah[m], bl[n], acc[m][n], 0, 0, 0);
            }
        __syncthreads();
    }

    // epilogue: celu + W3-weight, reduce over 128 cols of this tile
    float s[4][4] = {};
#pragma unroll
    for (int n = 0; n < 4; n++) {
        int col = n0 + wc * 64 + n * 16 + (lane & 15);
        float bbv = b2[e * HID + col];
        float w3 = W3[e * HID + col];
#pragma unroll
        for (int m = 0; m < 4; m++)
#pragma unroll
            for (int r = 0; r < 4; r++)
                s[m][r] += celu1(acc[m][n][r] + bbv) * w3;
    }
#pragma unroll
    for (int m = 0; m < 4; m++)
#pragma unroll
        for (int r = 0; r < 4; r++) {
#pragma unroll
            for (int off = 8; off > 0; off >>= 1)
                s[m][r] += __shfl_xor(s[m][r], off, 64);
        }
    if ((lane & 15) == 0) {
#pragma unroll
        for (int m = 0; m < 4; m++) {
            int rbase = m0 + wr * 64 + m * 16 + (lane >> 4) * 4;
#pragma unroll
            for (int r = 0; r < 4; r++)
                if (rbase + r < count)
                    atomicAdd(&hfinC[e * ESTR + rbase + r], s[m][r]);
        }
    }
}

// ---------------------------------------------------------------------------
__global__ __launch_bounds__(256) void k_out(
    const int* __restrict__ lt, const float* __restrict__ yref,
    const float* __restrict__ alpha, const int* __restrict__ rcnt,
    const int* __restrict__ ridxP, const int* __restrict__ post,
    const float* __restrict__ hfinC, float* __restrict__ out) {
    int t = blockIdx.x * 4 + (threadIdx.x >> 6);
    int lane = threadIdx.x & 63;
    if (t >= NTR) return;
    int lab = lt[t];
    int e = lab - 1;
    float ht = hfinC[e * ESTR + post[t]];
    float a = alpha[e];
    int n = rcnt[e];
    const int* lst = ridxP + e * NREF;
    float num = 0.f, den = 0.f;
    for (int i = lane; i < n; i += 64) {
        int pk = lst[i];
        int r = pk & 0xFFFF;
        int pq = pk >> 16;
        float d = fabsf(ht - hfinC[e * ESTR + pq]);
        float p = expf(-a * d);
        num += p * yref[r];
        den += p;
    }
#pragma unroll
    for (int o = 32; o > 0; o >>= 1) {
        num += __shfl_down(num, o, 64);
        den += __shfl_down(den, o, 64);
    }
    if (lane == 0) {
        out[t] = (float)lab;
        out[NTR + t] = num / den;
    }
}

extern "C" void kernel_launch(void* const* d_in, const int* in_sizes, int n_in,
                              void* d_out, int out_size, void* d_ws, size_t ws_size,
                              hipStream_t stream) {
    const float* xr    = (const float*)d_in[0];
    const float* yref  = (const float*)d_in[1];
    const int*   lr    = (const int*)  d_in[2];
    const float* xt    = (const float*)d_in[3];
    const int*   lt    = (const int*)  d_in[4];
    const float* W1    = (const float*)d_in[5];
    const float* b1    = (const float*)d_in[6];
    const float* W2    = (const float*)d_in[7];
    const float* b2    = (const float*)d_in[8];
    const float* W3    = (const float*)d_in[9];
    // d_in[10] = b3 (cancels in |ht-hr|), d_in[11] = alpha
    const float* alpha = (const float*)d_in[11];

    char* ws = (char*)d_ws;
    int*   cnt   = (int*)(ws + WS_CNT);
    int*   rcnt  = (int*)(ws + WS_RCNT);
    int*   post  = (int*)(ws + WS_POST);
    int*   ridxP = (int*)(ws + WS_RIDX);
    int*   comb  = (int*)(ws + WS_COMB);
    short* W1Th  = (short*)(ws + WS_W1TH);
    short* W1Tl  = (short*)(ws + WS_W1TL);
    short* XgH   = (short*)(ws + WS_XGH);
    short* XgL   = (short*)(ws + WS_XGL);
    short* W2Th  = (short*)(ws + WS_W2TH);   // aliases XgH (Xg dead after k_l1)
    short* W2Tl  = (short*)(ws + WS_W2TL);   // aliases XgL
    short* H1h   = (short*)(ws + WS_H1H);
    short* H1l   = (short*)(ws + WS_H1L);
    float* hfinC = (float*)(ws + WS_HFIN);
    float* out   = (float*)d_out;

    hipMemsetAsync(ws, 0, 32, stream);                      // cnt + rcnt

    k_compact<<<NCOMB / 256, 256, 0, stream>>>(lr, lt, cnt, rcnt, comb, ridxP, post);

    k_prep<<<PREP_ZERO, 256, 0, stream>>>(W1, xr, xt, cnt, comb,
                                          W1Th, W1Tl, XgH, XgL, hfinC);

    k_l1<<<8 * MT * NE, 256, 0, stream>>>(XgH, XgL, W1Th, W1Tl, b1, cnt, H1h, H1l);

    // W2 transpose AFTER k_l1 (it overwrites the Xg region)
    k_tr2<<<dim3(HID / 32, HID / 32, NE), 256, 0, stream>>>(W2, W2Th, W2Tl);

    k_l23<<<8 * MT * NE, 256, 0, stream>>>(H1h, H1l, W2Th, W2Tl, b2, W3, cnt, hfinC);

    k_out<<<NTR / 4, 256, 0, stream>>>(lt, yref, alpha, rcnt, ridxP, post, hfinC, out);
}